// Round 2
// baseline (1439.789 us; speedup 1.0000x reference)
//
#include <hip/hip_runtime.h>
#include <cstddef>
#include <cstdint>

#define PI_F    3.14159265358979323846f
#define TWOPI_F 6.28318530717958647692f

// B=8, C=64, H=256, W=512, WF=64, RANK=32, N=H*W=131072
// d_out (67,108,864 floats) doubles as scratch:
//   Zw/Zc: [0, 16777216)   Zh: [16777216, 33554432)   G: [33554432, 33816576)
// d_ws: only 65536 floats (256 KB) to stage Zc planes 0..1 for the last E launch.
#define ZH_OFF 16777216u
#define G_OFF  33554432u

// ---------------- filter: pool -> params -> softplus/tanh -> rank-sum -> G = filt-1 ----------------
__global__ __launch_bounds__(256) void k_filt(const float* __restrict__ x,
                                              const float* __restrict__ dt,
                                              const float* __restrict__ wmat,
                                              const float* __restrict__ bvec,
                                              float* __restrict__ G) {
    __shared__ float pooled[64 * 65];
    __shared__ float wsh[64 * 65];
    int t = threadIdx.x;
    int b = blockIdx.x >> 8, h = blockIdx.x & 255;
    for (int i = t; i < 4096; i += 256)
        wsh[(i >> 6) * 65 + (i & 63)] = wmat[i];
    for (int c = 0; c < 64; c++) {
        const float* xr = x + (((size_t)(b * 64 + c)) * 256 + h) * 512;
        float2 v = ((const float2*)xr)[t];
        float s = v.x + v.y;
        s += __shfl_xor(s, 1);
        s += __shfl_xor(s, 2);
        if ((t & 3) == 0) pooled[c * 65 + (t >> 2)] = s * 0.125f;
    }
    __syncthreads();
    float dtb = dt[b];
    int o = t & 63, q = t >> 6;
    float bo = bvec[o];
    for (int jj = 0; jj < 16; jj++) {
        int j = q * 16 + jj;
        float acc = bo;
        #pragma unroll 16
        for (int c = 0; c < 64; c++)
            acc = fmaf(wsh[o * 65 + c], pooled[c * 65 + j], acc);
        float nl;
        if (o < 32) nl = (acc > 20.0f) ? acc : log1pf(expf(acc));   // softplus -> nu
        else        nl = tanhf(acc) * PI_F;                          // theta
        float other = __shfl_xor(nl, 32);
        float nu = (o < 32) ? nl : other;
        float th = (o < 32) ? other : nl;
        float decay = expf(-nu * dtb);
        float sa, ca; sincosf(th * dtb, &sa, &ca);
        float tr = decay * ca, ti = decay * sa;
        #pragma unroll
        for (int off = 1; off < 64; off <<= 1) {
            tr += __shfl_xor(tr, off);
            ti += __shfl_xor(ti, off);
        }
        if ((t & 63) == 0) {
            float2 g = make_float2(0.5f * tr - 1.0f, 0.5f * ti);   // filt - 1
            ((float2*)G)[((size_t)b * 256 + h) * 64 + j] = g;
        }
    }
}

// ---------------- A: Zw[r][2wf+ri] = sum_w x[r][w] * e^{-2pi i w wf/512}, twiddles on-the-fly ----------------
__global__ __launch_bounds__(256) void k_gemmA(const float* __restrict__ x,
                                               float* __restrict__ Zw) {
    __shared__ __align__(16) float As[32][68];
    __shared__ __align__(16) float Bs[32][64];
    int t = threadIdx.x;
    int row0 = blockIdx.x * 64, n0 = blockIdx.y * 64;
    int lr = t >> 3, lk4 = (t & 7) << 2;
    int bkr = t >> 4, bc4 = (t & 15) << 2;
    int ty = t >> 4, tx = t & 15;
    // twiddle streams: two wf columns, u = e^{-2pi i (k0+bkr) wf/512}
    int wf0 = (n0 + bc4) >> 1;
    float u_r[2], u_i[2], c16r[2], c16i[2], advr[2], advi[2];
    #pragma unroll
    for (int q = 0; q < 2; q++) {
        int wf = wf0 + q;
        float s, c;
        sincosf((float)((bkr * wf) & 511) * (TWOPI_F / 512.0f), &s, &c);
        u_r[q] = c; u_i[q] = -s;
        sincosf((float)((16 * wf) & 511) * (TWOPI_F / 512.0f), &s, &c);
        c16r[q] = c; c16i[q] = -s;
        sincosf((float)((32 * wf) & 511) * (TWOPI_F / 512.0f), &s, &c);
        advr[q] = c; advi[q] = -s;
    }
    float acc[4][4] = {};
    size_t xrow0 = (size_t)(row0 + lr) * 512;
    size_t xrow1 = (size_t)(row0 + lr + 32) * 512;
    for (int k0 = 0; k0 < 512; k0 += 32) {
        __syncthreads();
        {
            float4 v = *(const float4*)(x + xrow0 + k0 + lk4);
            As[lk4 + 0][lr] = v.x; As[lk4 + 1][lr] = v.y;
            As[lk4 + 2][lr] = v.z; As[lk4 + 3][lr] = v.w;
        }
        {
            float4 v = *(const float4*)(x + xrow1 + k0 + lk4);
            int m = lr + 32;
            As[lk4 + 0][m] = v.x; As[lk4 + 1][m] = v.y;
            As[lk4 + 2][m] = v.z; As[lk4 + 3][m] = v.w;
        }
        *(float4*)&Bs[bkr][bc4] = make_float4(u_r[0], u_i[0], u_r[1], u_i[1]);
        {   // row bkr+16 = u * c16
            float r0 = u_r[0] * c16r[0] - u_i[0] * c16i[0];
            float i0 = u_r[0] * c16i[0] + u_i[0] * c16r[0];
            float r1 = u_r[1] * c16r[1] - u_i[1] * c16i[1];
            float i1 = u_r[1] * c16i[1] + u_i[1] * c16r[1];
            *(float4*)&Bs[bkr + 16][bc4] = make_float4(r0, i0, r1, i1);
        }
        #pragma unroll
        for (int q = 0; q < 2; q++) {   // advance by 32 k
            float nr = u_r[q] * advr[q] - u_i[q] * advi[q];
            float ni = u_r[q] * advi[q] + u_i[q] * advr[q];
            u_r[q] = nr; u_i[q] = ni;
        }
        __syncthreads();
        #pragma unroll
        for (int kk = 0; kk < 32; kk++) {
            float4 ra = *(const float4*)&As[kk][ty << 2];
            float4 rb = *(const float4*)&Bs[kk][tx << 2];
            float a[4] = {ra.x, ra.y, ra.z, ra.w};
            float bq[4] = {rb.x, rb.y, rb.z, rb.w};
            #pragma unroll
            for (int i = 0; i < 4; i++)
                #pragma unroll
                for (int j = 0; j < 4; j++)
                    acc[i][j] = fmaf(a[i], bq[j], acc[i][j]);
        }
    }
    #pragma unroll
    for (int i = 0; i < 4; i++) {
        int r = row0 + (ty << 2) + i;
        *(float4*)(Zw + (size_t)r * 128 + n0 + (tx << 2)) =
            make_float4(acc[i][0], acc[i][1], acc[i][2], acc[i][3]);
    }
}

// ---------------- B/D: complex GEMM vs on-the-fly 256-pt twiddles; optional *G epilogue ----------------
__global__ __launch_bounds__(256) void k_cgemm(const float* __restrict__ Zin,
                                               float* __restrict__ Zout,
                                               const float* __restrict__ G,
                                               float sign) {
    __shared__ __align__(16) float Tre[16][68], Tim[16][68];
    __shared__ __align__(16) float Zre[16][64], Zim[16][64];
    int t = threadIdx.x;
    int p = blockIdx.x;           // plane (b*64+c)
    int m0 = blockIdx.y * 64;     // output-row tile
    int ty = t >> 4, tx = t & 15;
    // twiddle: row m = m0 + (t>>2), k = k0 + jjB + d;  w = e^{sign*2pi i m k/256}
    int i_ = t >> 2, jjB = (t & 3) * 4;
    int m = m0 + i_;
    float wr[4], wi[4], ar, ai;
    #pragma unroll
    for (int d = 0; d < 4; d++) {
        float s, c;
        sincosf((float)((m * (jjB + d)) & 255) * (TWOPI_F / 256.0f), &s, &c);
        wr[d] = c; wi[d] = sign * s;
    }
    {
        float s, c;
        sincosf((float)((m * 16) & 255) * (TWOPI_F / 256.0f), &s, &c);
        ar = c; ai = sign * s;
    }
    float accR[4][4] = {}, accI[4][4] = {};
    size_t zbase = (size_t)p * 32768;
    for (int k0 = 0; k0 < 256; k0 += 16) {
        __syncthreads();
        #pragma unroll
        for (int d = 0; d < 4; d++) {
            Tre[jjB + d][i_] = wr[d];
            Tim[jjB + d][i_] = wi[d];
        }
        #pragma unroll
        for (int d = 0; d < 4; d++) {   // advance by 16 k
            float nr = wr[d] * ar - wi[d] * ai;
            float ni = wr[d] * ai + wi[d] * ar;
            wr[d] = nr; wi[d] = ni;
        }
        {   // Z tile: 16 k-rows x 64 complex
            int jr = t >> 4, c4 = t & 15;
            #pragma unroll
            for (int pass = 0; pass < 2; pass++) {
                int cc = c4 + pass * 16;
                float4 v = *(const float4*)(Zin + zbase + (size_t)(k0 + jr) * 128 + (size_t)cc * 4);
                Zre[jr][cc * 2]     = v.x; Zim[jr][cc * 2]     = v.y;
                Zre[jr][cc * 2 + 1] = v.z; Zim[jr][cc * 2 + 1] = v.w;
            }
        }
        __syncthreads();
        #pragma unroll
        for (int kk = 0; kk < 16; kk++) {
            float4 t_r = *(const float4*)&Tre[kk][ty << 2];
            float4 t_i = *(const float4*)&Tim[kk][ty << 2];
            float4 z_r = *(const float4*)&Zre[kk][tx << 2];
            float4 z_i = *(const float4*)&Zim[kk][tx << 2];
            float tr[4] = {t_r.x, t_r.y, t_r.z, t_r.w};
            float ti[4] = {t_i.x, t_i.y, t_i.z, t_i.w};
            float zr[4] = {z_r.x, z_r.y, z_r.z, z_r.w};
            float zi[4] = {z_i.x, z_i.y, z_i.z, z_i.w};
            #pragma unroll
            for (int i = 0; i < 4; i++)
                #pragma unroll
                for (int j = 0; j < 4; j++) {
                    accR[i][j] = fmaf(tr[i], zr[j], accR[i][j]);
                    accR[i][j] = fmaf(-ti[i], zi[j], accR[i][j]);
                    accI[i][j] = fmaf(tr[i], zi[j], accI[i][j]);
                    accI[i][j] = fmaf(ti[i], zr[j], accI[i][j]);
                }
        }
    }
    int b = p >> 6;
    #pragma unroll
    for (int i = 0; i < 4; i++) {
        int mm = m0 + (ty << 2) + i;
        float r[4], im[4];
        #pragma unroll
        for (int j = 0; j < 4; j++) { r[j] = accR[i][j]; im[j] = accI[i][j]; }
        if (G) {
            const float4* gp = (const float4*)(G + (((size_t)b * 256 + mm) * 64 + (tx << 2)) * 2);
            float4 g01 = gp[0], g23 = gp[1];
            float gr[4] = {g01.x, g01.z, g23.x, g23.z};
            float gi[4] = {g01.y, g01.w, g23.y, g23.w};
            #pragma unroll
            for (int j = 0; j < 4; j++) {
                float nr = r[j] * gr[j] - im[j] * gi[j];
                float ni = r[j] * gi[j] + im[j] * gr[j];
                r[j] = nr; im[j] = ni;
            }
        }
        float* dst = Zout + zbase + (size_t)mm * 128 + (size_t)(tx << 3);
        *(float4*)dst       = make_float4(r[0], im[0], r[1], im[1]);
        *(float4*)(dst + 4) = make_float4(r[2], im[2], r[3], im[3]);
    }
}

// ---------------- E: out = x + Zc (rows x 128) * S (128 x 512), S on-the-fly ----------------
__global__ __launch_bounds__(256) void k_gemmE(const float* __restrict__ Zc,
                                               const float* __restrict__ x,
                                               float* __restrict__ out,
                                               int rowLo) {
    __shared__ __align__(16) float As[32][68];
    __shared__ __align__(16) float Bs[32][64];
    int t = threadIdx.x;
    int row0 = rowLo + blockIdx.x * 64, n0 = blockIdx.y * 64;
    int lr = t >> 3, lk4 = (t & 7) << 2;
    int bkr = t >> 4, bc4 = (t & 15) << 2;
    int ty = t >> 4, tx = t & 15;
    const float invN = 1.0f / 131072.0f;
    int par = bkr & 1;          // S-row parity: 0 -> Re, 1 -> Im
    int wfh = bkr >> 1;         // wf for row k0+bkr is k0/2 + wfh
    // per-w streams: u = e^{-2pi i w wf/512} at wf = k0/2 + wfh
    float u_r[4], u_i[4], c8r[4], c8i[4], advr[4], advi[4];
    #pragma unroll
    for (int d = 0; d < 4; d++) {
        int w = n0 + bc4 + d;
        float s, c;
        sincosf((float)((w * wfh) & 511) * (TWOPI_F / 512.0f), &s, &c);
        u_r[d] = c; u_i[d] = -s;
        sincosf((float)((w * 8) & 511) * (TWOPI_F / 512.0f), &s, &c);
        c8r[d] = c; c8i[d] = -s;
        sincosf((float)((w * 16) & 511) * (TWOPI_F / 512.0f), &s, &c);
        advr[d] = c; advi[d] = -s;
    }
    float acc[4][4] = {};
    for (int k0 = 0; k0 < 128; k0 += 32) {
        __syncthreads();
        {
            float4 v = *(const float4*)(Zc + (size_t)(row0 + lr) * 128 + k0 + lk4);
            As[lk4 + 0][lr] = v.x; As[lk4 + 1][lr] = v.y;
            As[lk4 + 2][lr] = v.z; As[lk4 + 3][lr] = v.w;
        }
        {
            float4 v = *(const float4*)(Zc + (size_t)(row0 + lr + 32) * 128 + k0 + lk4);
            int mm = lr + 32;
            As[lk4 + 0][mm] = v.x; As[lk4 + 1][mm] = v.y;
            As[lk4 + 2][mm] = v.z; As[lk4 + 3][mm] = v.w;
        }
        int wf1 = (k0 >> 1) + wfh;
        float a1 = ((wf1 == 0) ? 1.0f : 2.0f) * invN;
        float a2 = 2.0f * invN;                  // wf1 + 8 >= 8, never DC
        float b1[4], b2[4];
        #pragma unroll
        for (int d = 0; d < 4; d++) {
            b1[d] = a1 * (par ? u_i[d] : u_r[d]);
            float vr = u_r[d] * c8r[d] - u_i[d] * c8i[d];
            float vi = u_r[d] * c8i[d] + u_i[d] * c8r[d];
            b2[d] = a2 * (par ? vi : vr);
            float nr = u_r[d] * advr[d] - u_i[d] * advi[d];   // advance wf += 16
            float ni = u_r[d] * advi[d] + u_i[d] * advr[d];
            u_r[d] = nr; u_i[d] = ni;
        }
        *(float4*)&Bs[bkr][bc4]      = make_float4(b1[0], b1[1], b1[2], b1[3]);
        *(float4*)&Bs[bkr + 16][bc4] = make_float4(b2[0], b2[1], b2[2], b2[3]);
        __syncthreads();
        #pragma unroll
        for (int kk = 0; kk < 32; kk++) {
            float4 ra = *(const float4*)&As[kk][ty << 2];
            float4 rb = *(const float4*)&Bs[kk][tx << 2];
            float a[4] = {ra.x, ra.y, ra.z, ra.w};
            float bq[4] = {rb.x, rb.y, rb.z, rb.w};
            #pragma unroll
            for (int i = 0; i < 4; i++)
                #pragma unroll
                for (int j = 0; j < 4; j++)
                    acc[i][j] = fmaf(a[i], bq[j], acc[i][j]);
        }
    }
    #pragma unroll
    for (int i = 0; i < 4; i++) {
        int r = row0 + (ty << 2) + i;
        size_t grow = (size_t)r * 512;
        float4 xv = *(const float4*)(x + grow + n0 + (tx << 2));
        *(float4*)(out + grow + n0 + (tx << 2)) =
            make_float4(acc[i][0] + xv.x, acc[i][1] + xv.y,
                        acc[i][2] + xv.z, acc[i][3] + xv.w);
    }
}

// ---------------- stage Zc planes 0..1 (65536 floats) into ws ----------------
__global__ __launch_bounds__(256) void k_copy(const float* __restrict__ src,
                                              float* __restrict__ dst) {
    int i = blockIdx.x * 256 + threadIdx.x;
    ((float4*)dst)[i] = ((const float4*)src)[i];
}

extern "C" void kernel_launch(void* const* d_in, const int* in_sizes, int n_in,
                              void* d_out, int out_size, void* d_ws, size_t ws_size,
                              hipStream_t stream) {
    (void)in_sizes; (void)n_in; (void)out_size; (void)ws_size;
    const float* x    = (const float*)d_in[0];
    const float* dt   = (const float*)d_in[1];
    const float* wmat = (const float*)d_in[2];
    const float* bvec = (const float*)d_in[3];
    float* out = (float*)d_out;
    float* ws  = (float*)d_ws;

    float* G   = out + G_OFF;     // [33.55M, 33.82M) floats of d_out
    float* Zw  = out;             // [0, 16.77M)
    float* Zh  = out + ZH_OFF;    // [16.77M, 33.55M)
    float* Zc  = out;             // reuses Zw region
    float* stg = ws;              // 65536 floats = 256 KB

    k_filt <<<2048,            256, 0, stream>>>(x, dt, wmat, bvec, G);
    k_gemmA<<<dim3(2048, 2),   256, 0, stream>>>(x, Zw);
    k_cgemm<<<dim3(512, 4),    256, 0, stream>>>(Zw, Zh, G, -1.0f);   // fwd h-DFT + filter
    k_cgemm<<<dim3(512, 4),    256, 0, stream>>>(Zh, Zc, nullptr, 1.0f); // inv h-DFT
    k_copy <<<64,              256, 0, stream>>>(Zc, stg);
    // Descending-plane cascade: out plane p clobbers Zc planes 4p..4p+3,
    // which are only read by strictly earlier launches.
    k_gemmE<<<dim3(1536, 8),   256, 0, stream>>>(Zc,  x, out, 128 * 256); // planes 128..511
    k_gemmE<<<dim3(384, 8),    256, 0, stream>>>(Zc,  x, out, 32 * 256);  // planes 32..127
    k_gemmE<<<dim3(96, 8),     256, 0, stream>>>(Zc,  x, out, 8 * 256);   // planes 8..31
    k_gemmE<<<dim3(24, 8),     256, 0, stream>>>(Zc,  x, out, 2 * 256);   // planes 2..7
    k_gemmE<<<dim3(8, 8),      256, 0, stream>>>(stg, x, out, 0);         // planes 0..1 (staged)
}